// Round 4
// baseline (583.052 us; speedup 1.0000x reference)
//
#include <hip/hip_runtime.h>
#include <hip/hip_fp16.h>

// Coalesced + batched-MLP version. Every vmem instr: lane i at base + i*16B.
// All 8 loads (4xA, 4xB) issue back-to-back before any shfl/compute, so the
// wave keeps 8 KiB outstanding and overlaps compute of group k with loads of
// k+1..3. Row gather via shfl_xor(1)/shfl_xor(2) nibble OR-combine within
// 4-lane groups (DPP quad-perm); all 4 lanes redundantly do the fp16 add
// (VALU ~90% idle) and each stores its own quarter -> coalesced NT store.

typedef float float4_n __attribute__((ext_vector_type(4)));  // native vec for NT builtin

__global__ __launch_bounds__(256) void spike_fp16_add_kernel(
    const float4* __restrict__ A, const float4* __restrict__ B,
    float4* __restrict__ O, int nf4)   // nf4 = total float4 count = nrows*4
{
    const int lane = threadIdx.x & 63;
    const int waveBase = ((blockIdx.x * blockDim.x + threadIdx.x) >> 6) * 256;
    const int q = lane & 3;
    const int sh = 12 - 4 * q;          // MSB-first nibble position for this quarter
    const int idx = waveBase + lane;

    if (waveBase + 255 < nf4) {         // wave-uniform fast path
        float4 a[4], b[4];
        #pragma unroll
        for (int k = 0; k < 4; ++k) a[k] = A[idx + k * 64];
        #pragma unroll
        for (int k = 0; k < 4; ++k) b[k] = B[idx + k * 64];

        #pragma unroll
        for (int k = 0; k < 4; ++k) {
            uint32_t ua = (((uint32_t)a[k].x << 3) | ((uint32_t)a[k].y << 2) |
                           ((uint32_t)a[k].z << 1) |  (uint32_t)a[k].w) << sh;
            uint32_t ub = (((uint32_t)b[k].x << 3) | ((uint32_t)b[k].y << 2) |
                           ((uint32_t)b[k].z << 1) |  (uint32_t)b[k].w) << sh;

            ua |= (uint32_t)__shfl_xor((int)ua, 1);
            ua |= (uint32_t)__shfl_xor((int)ua, 2);
            ub |= (uint32_t)__shfl_xor((int)ub, 1);
            ub |= (uint32_t)__shfl_xor((int)ub, 2);

            float fa = __half2float(__ushort_as_half((unsigned short)ua));
            float fb = __half2float(__ushort_as_half((unsigned short)ub));
            uint32_t us = (uint32_t)__half_as_ushort(__float2half_rn(fa + fb));

            uint32_t ns = (us >> sh) & 0xFu;
            float4_n o;
            o.x = (float)((ns >> 3) & 1u);
            o.y = (float)((ns >> 2) & 1u);
            o.z = (float)((ns >> 1) & 1u);
            o.w = (float)( ns       & 1u);
            __builtin_nontemporal_store(o, (float4_n*)&O[idx + k * 64]);
        }
    } else {                            // tail (not hit at N=4194304)
        for (int k = 0; k < 4; ++k) {
            int f4 = idx + k * 64;
            uint32_t ua = 0, ub = 0;
            if (f4 < nf4) {
                float4 a = A[f4], b = B[f4];
                ua = (((uint32_t)a.x << 3) | ((uint32_t)a.y << 2) |
                      ((uint32_t)a.z << 1) |  (uint32_t)a.w) << sh;
                ub = (((uint32_t)b.x << 3) | ((uint32_t)b.y << 2) |
                      ((uint32_t)b.z << 1) |  (uint32_t)b.w) << sh;
            }
            ua |= (uint32_t)__shfl_xor((int)ua, 1);
            ua |= (uint32_t)__shfl_xor((int)ua, 2);
            ub |= (uint32_t)__shfl_xor((int)ub, 1);
            ub |= (uint32_t)__shfl_xor((int)ub, 2);
            float fa = __half2float(__ushort_as_half((unsigned short)ua));
            float fb = __half2float(__ushort_as_half((unsigned short)ub));
            uint32_t us = (uint32_t)__half_as_ushort(__float2half_rn(fa + fb));
            uint32_t ns = (us >> sh) & 0xFu;
            float4 o;
            o.x = (float)((ns >> 3) & 1u);
            o.y = (float)((ns >> 2) & 1u);
            o.z = (float)((ns >> 1) & 1u);
            o.w = (float)( ns       & 1u);
            if (f4 < nf4) O[f4] = o;
        }
    }
}

extern "C" void kernel_launch(void* const* d_in, const int* in_sizes, int n_in,
                              void* d_out, int out_size, void* d_ws, size_t ws_size,
                              hipStream_t stream) {
    const float4* A = (const float4*)d_in[0];
    const float4* B = (const float4*)d_in[1];
    float4* O = (float4*)d_out;

    int nf4 = in_sizes[0] / 4;          // total float4s per input
    int block = 256;
    int threads = (nf4 + 3) / 4;        // each thread handles 4 float4s
    int grid = (threads + block - 1) / block;
    spike_fp16_add_kernel<<<grid, block, 0, stream>>>(A, B, O, nf4);
}